// Round 16
// baseline (54.597 us; speedup 1.0000x reference)
//
#include <hip/hip_runtime.h>
#include <math.h>

typedef __attribute__((ext_vector_type(8))) short short8;
typedef __attribute__((ext_vector_type(4))) float f32x4;

#define SCALE 0.08838834764831845f   // 1/sqrt(128)

// LDS: W1T hi/lo 16K | L_G: W2T-scratch -> (G -> Zk per scene) hi/lo 16K |
//      L_XH: W3-scratch (32K) -> 4 waves x 2 A-planes x 4K | ck | g
#define L_W1T 0
#define L_G   16384
#define L_XH  32768
#define L_CK  65536
#define L_g2  65792
#define LDS_BYTES 66048

__device__ __forceinline__ f32x4 mk4(float v) { f32x4 r = {v, v, v, v}; return r; }
union U4S8 { uint4 u4; unsigned u[4]; short8 s; };

// hi word from two raw f32 bit-patterns + lo word from trunc residuals
#define RESID2(DH, DL, UA, UB) do {                                     \
    (DH) = __builtin_amdgcn_perm((UB), (UA), 0x07060302u);              \
    float _ra = __uint_as_float(UA) - __uint_as_float((UA) & 0xffff0000u); \
    float _rb = __uint_as_float(UB) - __uint_as_float((UB) & 0xffff0000u); \
    (DL) = __builtin_amdgcn_perm(__float_as_uint(_rb),                  \
                                 __float_as_uint(_ra), 0x07060302u);    \
} while (0)

// two uint4 of raw f32 -> hi/lo short8 frags
#define SPLIT8R(SH, SL, A, B) do {                                      \
    U4S8 _th, _tl;                                                      \
    RESID2(_th.u[0], _tl.u[0], (A).x, (A).y);                           \
    RESID2(_th.u[1], _tl.u[1], (A).z, (A).w);                           \
    RESID2(_th.u[2], _tl.u[2], (B).x, (B).y);                           \
    RESID2(_th.u[3], _tl.u[3], (B).z, (B).w);                           \
    SH = _th.s; SL = _tl.s;                                             \
} while (0)

// ---- DPP 16-lane reductions (row_ror tree, pure VALU) ----
#define DPP_ROR(V, CTRL) \
    __int_as_float(__builtin_amdgcn_update_dpp(0, __float_as_int(V), (CTRL), 0xf, 0xf, true))
#define RED16_MAX(M) do {                                               \
    (M) = fmaxf((M), DPP_ROR((M), 0x128));                              \
    (M) = fmaxf((M), DPP_ROR((M), 0x124));                              \
    (M) = fmaxf((M), DPP_ROR((M), 0x122));                              \
    (M) = fmaxf((M), DPP_ROR((M), 0x121));                              \
} while (0)
#define RED16_SUM(S) do {                                               \
    (S) += DPP_ROR((S), 0x128);                                         \
    (S) += DPP_ROR((S), 0x124);                                         \
    (S) += DPP_ROR((S), 0x122);                                         \
    (S) += DPP_ROR((S), 0x121);                                         \
} while (0)

#define RELU4(ACC) do {                                                  \
    _Pragma("unroll")                                                    \
    for (int _n = 0; _n < 4; ++_n) {                                     \
        _Pragma("unroll")                                                \
        for (int _r = 0; _r < 4; ++_r)                                   \
            (ACC)[_n][_r] = fmaxf((ACC)[_n][_r], 0.f);                   \
    }                                                                    \
} while (0)

// ---- per-quarter PE + bias feature 42 = 1.0 (uniform sincos) ----
__device__ __forceinline__ void pe_values(float* v, const float* __restrict__ pose, int qt) {
    float2 r0 = *(const float2*)(pose + 2);
    float2 r1 = *(const float2*)(pose + 6);
    float2 r2 = *(const float2*)(pose + 10);
    const float L[3] = {r0.y, r1.y, r2.y};
    const float sc = (qt == 0) ? 1.5f : ((qt == 1) ? 6.f : 24.f);
    float s0[3], c0[3], s1[3], c1[3], s2[3], c2[3];
#pragma unroll
    for (int c = 0; c < 3; ++c) {
        __sincosf(sc * L[c], &s0[c], &c0[c]);
        s1[c] = 2.f * s0[c] * c0[c];
        c1[c] = fmaf(c0[c], c0[c], -s0[c] * s0[c]);
        s2[c] = 2.f * s1[c] * c1[c];
        c2[c] = fmaf(c1[c], c1[c], -s1[c] * s1[c]);
    }
    if (qt == 0) {
        v[0]=L[0]; v[1]=L[1]; v[2]=L[2];
        v[3]=s0[0]; v[4]=s0[1]; v[5]=s0[2];
        v[6]=c0[0]; v[7]=c0[1]; v[8]=c0[2];
        v[9]=s1[0]; v[10]=s1[1]; v[11]=s1[2];
        v[12]=c1[0]; v[13]=c1[1]; v[14]=c1[2];
        v[15]=s2[0];
    } else if (qt == 1) {
        v[0]=s0[1]; v[1]=s0[2];
        v[2]=c0[0]; v[3]=c0[1]; v[4]=c0[2];
        v[5]=s1[0]; v[6]=s1[1]; v[7]=s1[2];
        v[8]=c1[0]; v[9]=c1[1]; v[10]=c1[2];
        v[11]=s2[0]; v[12]=s2[1]; v[13]=s2[2];
        v[14]=c2[0]; v[15]=c2[1];
    } else if (qt == 2) {
        v[0]=c0[2];
        v[1]=s1[0]; v[2]=s1[1]; v[3]=s1[2];
        v[4]=c1[0]; v[5]=c1[1]; v[6]=c1[2];
        v[7]=r0.x; v[8]=r1.x; v[9]=r2.x;
        v[10]=1.0f;   // bias feature 42
        v[11]=0.f; v[12]=0.f; v[13]=0.f; v[14]=0.f; v[15]=0.f;
    } else {
#pragma unroll
        for (int t = 0; t < 16; ++t) v[t] = 0.f;
    }
}

// pack v[16] -> X hi/lo halves of a 4K plane (bf16 planes, frag-ready)
__device__ __forceinline__ void writeA16(char* X, int l15, int swz, int qt, const float* v) {
    unsigned h[8], l[8];
#pragma unroll
    for (int p = 0; p < 8; ++p) {
        float a = v[2 * p], b = v[2 * p + 1];
        unsigned ua = __float_as_uint(a), ub = __float_as_uint(b);
        h[p] = (ub & 0xffff0000u) | (ua >> 16);
        float ra = a - __uint_as_float(ua & 0xffff0000u);
        float rb = b - __uint_as_float(ub & 0xffff0000u);
        l[p] = (__float_as_uint(rb) & 0xffff0000u) | (__float_as_uint(ra) >> 16);
    }
    const int cb = qt * 32;
    const int a1 = l15 * 128 + (cb ^ swz);
    const int a2 = l15 * 128 + ((cb + 16) ^ swz);
    *(uint4*)(X + a1) = make_uint4(h[0], h[1], h[2], h[3]);
    *(uint4*)(X + a2) = make_uint4(h[4], h[5], h[6], h[7]);
    *(uint4*)(X + 2048 + a1) = make_uint4(l[0], l[1], l[2], l[3]);
    *(uint4*)(X + 2048 + a2) = make_uint4(l[4], l[5], l[6], l[7]);
}

// A-frags (both ks) from RAW-f32 H plane: 4 b128 reads + trunc-split reconstruct
#define READ_A(H, Ah0, Al0, Ah1, Al1) do {                              \
    uint4 _a = *(const uint4*)((H) + hb00);                             \
    uint4 _b = *(const uint4*)((H) + hb01);                             \
    uint4 _c = *(const uint4*)((H) + hb10);                             \
    uint4 _d = *(const uint4*)((H) + hb11);                             \
    SPLIT8R(Ah0, Al0, _a, _b);                                          \
    SPLIT8R(Ah1, Al1, _c, _d);                                          \
} while (0)

// single-tile hi/lo gemm, B planes in LDS (hi @BP, lo @BP+8192)
#define GEMM6_LDS(ACC, Ah0, Al0, Ah1, Al1, BP) do {                     \
    _Pragma("unroll")                                                   \
    for (int _nt = 0; _nt < 4; ++_nt) {                                 \
        const char* _b = (BP) + _nt * 2048;                             \
        short8 _bh0 = *(const short8*)(_b + aoff0);                     \
        short8 _bl0 = *(const short8*)(_b + 8192 + aoff0);              \
        short8 _bh1 = *(const short8*)(_b + aoff1);                     \
        short8 _bl1 = *(const short8*)(_b + 8192 + aoff1);              \
        f32x4 _x = (ACC)[_nt];                                          \
        _x = __builtin_amdgcn_mfma_f32_16x16x32_bf16(Ah0, _bh0, _x, 0, 0, 0); \
        _x = __builtin_amdgcn_mfma_f32_16x16x32_bf16(Ah0, _bl0, _x, 0, 0, 0); \
        _x = __builtin_amdgcn_mfma_f32_16x16x32_bf16(Al0, _bh0, _x, 0, 0, 0); \
        _x = __builtin_amdgcn_mfma_f32_16x16x32_bf16(Ah1, _bh1, _x, 0, 0, 0); \
        _x = __builtin_amdgcn_mfma_f32_16x16x32_bf16(Ah1, _bl1, _x, 0, 0, 0); \
        _x = __builtin_amdgcn_mfma_f32_16x16x32_bf16(Al1, _bh1, _x, 0, 0, 0); \
        (ACC)[_nt] = _x;                                                \
    }                                                                   \
} while (0)

// pair gemm: B-frags read ONCE from LDS, feed both tiles
#define GEMM6_LDS_PAIR(ACCA, Aa0, Aal0, Aa1, Aal1, ACCB, Bb0, Bbl0, Bb1, Bbl1, BP) do { \
    _Pragma("unroll")                                                   \
    for (int _nt = 0; _nt < 4; ++_nt) {                                 \
        const char* _b = (BP) + _nt * 2048;                             \
        short8 _bh0 = *(const short8*)(_b + aoff0);                     \
        short8 _bl0 = *(const short8*)(_b + 8192 + aoff0);              \
        short8 _bh1 = *(const short8*)(_b + aoff1);                     \
        short8 _bl1 = *(const short8*)(_b + 8192 + aoff1);              \
        f32x4 _x = (ACCA)[_nt];                                         \
        _x = __builtin_amdgcn_mfma_f32_16x16x32_bf16(Aa0, _bh0, _x, 0, 0, 0); \
        _x = __builtin_amdgcn_mfma_f32_16x16x32_bf16(Aa0, _bl0, _x, 0, 0, 0); \
        _x = __builtin_amdgcn_mfma_f32_16x16x32_bf16(Aal0, _bh0, _x, 0, 0, 0); \
        _x = __builtin_amdgcn_mfma_f32_16x16x32_bf16(Aa1, _bh1, _x, 0, 0, 0); \
        _x = __builtin_amdgcn_mfma_f32_16x16x32_bf16(Aa1, _bl1, _x, 0, 0, 0); \
        _x = __builtin_amdgcn_mfma_f32_16x16x32_bf16(Aal1, _bh1, _x, 0, 0, 0); \
        (ACCA)[_nt] = _x;                                               \
        f32x4 _y = (ACCB)[_nt];                                         \
        _y = __builtin_amdgcn_mfma_f32_16x16x32_bf16(Bb0, _bh0, _y, 0, 0, 0); \
        _y = __builtin_amdgcn_mfma_f32_16x16x32_bf16(Bb0, _bl0, _y, 0, 0, 0); \
        _y = __builtin_amdgcn_mfma_f32_16x16x32_bf16(Bbl0, _bh0, _y, 0, 0, 0); \
        _y = __builtin_amdgcn_mfma_f32_16x16x32_bf16(Bb1, _bh1, _y, 0, 0, 0); \
        _y = __builtin_amdgcn_mfma_f32_16x16x32_bf16(Bb1, _bl1, _y, 0, 0, 0); \
        _y = __builtin_amdgcn_mfma_f32_16x16x32_bf16(Bbl1, _bh1, _y, 0, 0, 0); \
        (ACCB)[_nt] = _y;                                               \
    }                                                                   \
} while (0)

// hi/lo gemm, B fragments in registers (W2T)
#define GEMM6_REG(ACC, Ah0, Al0, Ah1, Al1, Bh, Bl) do {                 \
    _Pragma("unroll")                                                   \
    for (int _nt = 0; _nt < 4; ++_nt) {                                 \
        f32x4 _x = (ACC)[_nt];                                          \
        _x = __builtin_amdgcn_mfma_f32_16x16x32_bf16(Ah0, (Bh)[0][_nt], _x, 0, 0, 0); \
        _x = __builtin_amdgcn_mfma_f32_16x16x32_bf16(Ah0, (Bl)[0][_nt], _x, 0, 0, 0); \
        _x = __builtin_amdgcn_mfma_f32_16x16x32_bf16(Al0, (Bh)[0][_nt], _x, 0, 0, 0); \
        _x = __builtin_amdgcn_mfma_f32_16x16x32_bf16(Ah1, (Bh)[1][_nt], _x, 0, 0, 0); \
        _x = __builtin_amdgcn_mfma_f32_16x16x32_bf16(Ah1, (Bl)[1][_nt], _x, 0, 0, 0); \
        _x = __builtin_amdgcn_mfma_f32_16x16x32_bf16(Al1, (Bh)[1][_nt], _x, 0, 0, 0); \
        (ACC)[_nt] = _x;                                                \
    }                                                                   \
} while (0)

// C-tile -> RAW-f32 H plane (16 plain b32 writes), swizzled
#define STORE_H(H, ACC) do {                                            \
    _Pragma("unroll")                                                   \
    for (int _nt = 0; _nt < 4; ++_nt) {                                 \
        _Pragma("unroll")                                               \
        for (int _r = 0; _r < 4; ++_r) {                                \
            int _row = q4 + _r;                                         \
            int _byte = _row * 256 + ((((l15 + 16 * _nt) << 2)) ^ ((_row & 7) << 4)); \
            *(float*)((H) + _byte) = (ACC)[_nt][_r];                    \
        }                                                               \
    }                                                                   \
} while (0)

// scatter an f32x4[4] tile (rows 16w+q4..+3, cols l15+16nt) as trunc hi/lo into plane P
#define SCATTER_TILE(P, ACC) do {                                       \
    _Pragma("unroll")                                                   \
    for (int _nt = 0; _nt < 4; ++_nt) {                                 \
        _Pragma("unroll")                                               \
        for (int _r = 0; _r < 4; ++_r) {                                \
            int _row = 16 * w + q4 + _r;                                \
            int _byte = _row * 128 + (((l15 + 16 * _nt) * 2) ^ ((_row & 7) << 4)); \
            float _v = (ACC)[_nt][_r];                                  \
            unsigned _u = __float_as_uint(_v);                          \
            *(unsigned short*)((P) + _byte) = (unsigned short)(_u >> 16); \
            float _res = _v - __uint_as_float(_u & 0xffff0000u);        \
            *(unsigned short*)((P) + 8192 + _byte) =                    \
                (unsigned short)(__float_as_uint(_res) >> 16);          \
        }                                                               \
    }                                                                   \
} while (0)

#define SOFTMAX_STORE(ACC, QOFF) do {                                   \
    _Pragma("unroll")                                                   \
    for (int _r = 0; _r < 4; ++_r) {                                    \
        float _m = fmaxf(fmaxf((ACC)[0][_r], (ACC)[1][_r]),             \
                         fmaxf((ACC)[2][_r], (ACC)[3][_r]));            \
        RED16_MAX(_m);                                                  \
        float _e0 = __expf(((ACC)[0][_r] - _m) * SCALE);                \
        float _e1 = __expf(((ACC)[1][_r] - _m) * SCALE);                \
        float _e2 = __expf(((ACC)[2][_r] - _m) * SCALE);                \
        float _e3 = __expf(((ACC)[3][_r] - _m) * SCALE);                \
        float _ss = _e0 + _e1 + _e2 + _e3;                              \
        RED16_SUM(_ss);                                                 \
        float _iv = 1.f / _ss;                                          \
        (ACC)[0][_r] = _e0 * _iv; (ACC)[1][_r] = _e1 * _iv;             \
        (ACC)[2][_r] = _e2 * _iv; (ACC)[3][_r] = _e3 * _iv;             \
    }                                                                   \
    _Pragma("unroll")                                                   \
    for (int _nt = 0; _nt < 4; ++_nt) {                                 \
        int _k = l15 + 16 * _nt;                                        \
        *(float4*)(outS + (size_t)_k * 256 + (QOFF)) =                  \
            make_float4((ACC)[_nt][0], (ACC)[_nt][1],                   \
                        (ACC)[_nt][2], (ACC)[_nt][3]);                  \
    }                                                                   \
} while (0)

// ---- single fused kernel: 2 scenes per block, G resident in registers ----
__global__ __launch_bounds__(256, 2) void cam_mfma_kernel(
    const float* __restrict__ input_poses, const float* __restrict__ target_poses,
    const float* __restrict__ W1, const float* __restrict__ b1,
    const float* __restrict__ W2, const float* __restrict__ b2,
    const float* __restrict__ W3, const float* __restrict__ b3,
    float* __restrict__ out)
{
    __shared__ __align__(16) char smem[LDS_BYTES];
    const int tid = threadIdx.x, lane = tid & 63, w = tid >> 6;
    const int l15 = lane & 15, g = lane >> 4, q4 = g << 2;
    const int swz = (l15 & 7) << 4;
    const int aoff0 = l15 * 128 + ((g << 4) ^ swz);
    const int aoff1 = l15 * 128 + ((64 + (g << 4)) ^ swz);
    const int hb00 = l15 * 256 + ((32 * g) ^ swz);
    const int hb01 = l15 * 256 + ((32 * g + 16) ^ swz);
    const int hb10 = l15 * 256 + ((32 * g + 128) ^ swz);
    const int hb11 = l15 * 256 + ((32 * g + 128 + 16) ^ swz);

    char* ZK = smem + L_G;
    char* XA = smem + L_XH + (w << 13);
    char* XB = XA + 4096;
    float* ckF = (float*)(smem + L_CK);
    float* gF  = (float*)(smem + L_g2);

    // ---- P1: coalesced staging (once per block) ----
    {
        const uint4* src = (const uint4*)W3;
#pragma unroll
        for (int it = 0; it < 8; ++it) {
            int idx = tid + it * 256;
            int row = idx >> 5, c4 = idx & 31;
            *(uint4*)(smem + L_XH + row * 512 + ((c4 * 16) ^ ((row & 7) << 4))) = src[idx];
        }
    }
#pragma unroll
    for (int it = 0; it < 8; ++it) {
        int e = tid + it * 256;
        int i = e & 63, jp = e >> 6;
        int j0 = jp * 2, j1 = j0 + 1;
        float v0 = (j0 < 42) ? W1[j0 * 64 + i] : ((j0 == 42) ? b1[i] : 0.f);
        float v1 = (j1 < 42) ? W1[j1 * 64 + i] : ((j1 == 42) ? b1[i] : 0.f);
        unsigned dh, dl;
        RESID2(dh, dl, __float_as_uint(v0), __float_as_uint(v1));
        int a = i * 128 + ((jp * 4) ^ ((i & 7) << 4));
        *(unsigned*)(smem + L_W1T + a) = dh;
        *(unsigned*)(smem + L_W1T + 8192 + a) = dl;
        float u0 = W2[j0 * 64 + i], u1 = W2[j1 * 64 + i];
        RESID2(dh, dl, __float_as_uint(u0), __float_as_uint(u1));
        *(unsigned*)(smem + L_G + a) = dh;          // W2T scratch
        *(unsigned*)(smem + L_G + 8192 + a) = dl;
    }
    if (tid < 64) {
        const float4* wr = (const float4*)(W3 + tid * 128);
        const float4* br = (const float4*)b3;
        float a0 = 0.f, a1 = 0.f, a2 = 0.f, a3 = 0.f;
#pragma unroll 8
        for (int c = 0; c < 32; ++c) {
            float4 x = wr[c], y = br[c];
            a0 = fmaf(x.x, y.x, a0);
            a1 = fmaf(x.y, y.y, a1);
            a2 = fmaf(x.z, y.z, a2);
            a3 = fmaf(x.w, y.w, a3);
        }
        gF[tid] = (a0 + a1) + (a2 + a3);
    }
    __syncthreads();   // barrier A: W3/W1T/W2T staged, g ready

    // ---- P2: w2r frags; G = W3 W3^T slice via MFMA (kept RESIDENT in gacc) ----
    short8 w2h[2][4], w2l[2][4];
#pragma unroll
    for (int ks = 0; ks < 2; ++ks)
#pragma unroll
        for (int nt = 0; nt < 4; ++nt) {
            const char* bsc = smem + L_G + nt * 2048 + (ks ? aoff1 : aoff0);
            w2h[ks][nt] = *(const short8*)(bsc);
            w2l[ks][nt] = *(const short8*)(bsc + 8192);
        }
    f32x4 gacc[4];
    {
#pragma unroll
        for (int nt = 0; nt < 4; ++nt) gacc[nt] = mk4(0.f);
        const char* W3L = smem + L_XH;
        const int ra = 16 * w + l15;
#pragma unroll
        for (int ks = 0; ks < 4; ++ks) {
            const int cb = g * 32 + ks * 128;
            uint4 a0 = *(const uint4*)(W3L + ra * 512 + (cb ^ ((ra & 7) << 4)));
            uint4 a1 = *(const uint4*)(W3L + ra * 512 + ((cb + 16) ^ ((ra & 7) << 4)));
            short8 ah, al;
            SPLIT8R(ah, al, a0, a1);
#pragma unroll
            for (int nt = 0; nt < 4; ++nt) {
                const int rb = l15 + 16 * nt;
                uint4 b0 = *(const uint4*)(W3L + rb * 512 + (cb ^ ((rb & 7) << 4)));
                uint4 b1_ = *(const uint4*)(W3L + rb * 512 + ((cb + 16) ^ ((rb & 7) << 4)));
                short8 bh, bl;
                SPLIT8R(bh, bl, b0, b1_);
                f32x4 x = gacc[nt];
                x = __builtin_amdgcn_mfma_f32_16x16x32_bf16(ah, bh, x, 0, 0, 0);
                x = __builtin_amdgcn_mfma_f32_16x16x32_bf16(ah, bl, x, 0, 0, 0);
                x = __builtin_amdgcn_mfma_f32_16x16x32_bf16(al, bh, x, 0, 0, 0);
                gacc[nt] = x;
            }
        }
    }
    float b2v[4], gw[4];
#pragma unroll
    for (int nt = 0; nt < 4; ++nt) {
        b2v[nt] = b2[l15 + 16 * nt];
        gw[nt]  = gF[l15 + 16 * nt];
    }
    short8 Ah0, Al0, Ah1, Al1;
    float vA[16], vB[16];
    __syncthreads();   // barrier B: w2r loaded, W3/W2T scratch dead

    // ================= scene loop: 2 scenes per block =================
#pragma unroll 1
    for (int sc = 0; sc < 2; ++sc) {
        const int s = blockIdx.x * 2 + sc;
        if (sc > 0) __syncthreads();   // barrier S: prior scene's Zk/ck readers done

        SCATTER_TILE(smem + L_G, gacc);   // G slice -> L_G (from resident regs)
        pe_values(vA, input_poses + ((size_t)(s * 64 + 16 * w + l15)) * 16, g);

        // ---- key tile ----
        f32x4 zacc[4];
        {
            writeA16(XA, l15, swz, g, vA);
            Ah0 = *(const short8*)(XA + aoff0);
            Al0 = *(const short8*)(XA + 2048 + aoff0);
            Ah1 = *(const short8*)(XA + aoff1);
            Al1 = *(const short8*)(XA + 2048 + aoff1);
            f32x4 acc[4];
#pragma unroll
            for (int nt = 0; nt < 4; ++nt) acc[nt] = mk4(0.f);
            GEMM6_LDS(acc, Ah0, Al0, Ah1, Al1, smem + L_W1T);   // L1
            RELU4(acc);
            STORE_H(XA, acc);

            READ_A(XA, Ah0, Al0, Ah1, Al1);
#pragma unroll
            for (int nt = 0; nt < 4; ++nt) acc[nt] = mk4(b2v[nt]);
            GEMM6_REG(acc, Ah0, Al0, Ah1, Al1, w2h, w2l);        // L2
            RELU4(acc);

#pragma unroll
            for (int r = 0; r < 4; ++r) {                        // ck = g . h2k
                float t = acc[0][r] * gw[0];
                t = fmaf(acc[1][r], gw[1], t);
                t = fmaf(acc[2][r], gw[2], t);
                t = fmaf(acc[3][r], gw[3], t);
                RED16_SUM(t);
                if (l15 == 0) ckF[16 * w + q4 + r] = t;
            }
            STORE_H(XA, acc);                                    // H2

            READ_A(XA, Ah0, Al0, Ah1, Al1);
#pragma unroll
            for (int nt = 0; nt < 4; ++nt) zacc[nt] = mk4(0.f);
            __syncthreads();   // barrier C: all waves' G scatter visible
            GEMM6_LDS(zacc, Ah0, Al0, Ah1, Al1, smem + L_G);     // Zk = H2k @ G
        }
        pe_values(vA, target_poses + ((size_t)(s * 256 + (w) * 16 + l15)) * 16, g);
        pe_values(vB, target_poses + ((size_t)(s * 256 + (4 + w) * 16 + l15)) * 16, g);
        __syncthreads();   // barrier 1: all G reads + ck writes done

        SCATTER_TILE(ZK, zacc);            // Zk over G
        writeA16(XA, l15, swz, g, vA);     // pair-0 A tiles
        writeA16(XB, l15, swz, g, vB);
        __syncthreads();   // barrier 2: Zk + ck visible
        float ckreg[4];
#pragma unroll
        for (int nt = 0; nt < 4; ++nt) ckreg[nt] = ckF[l15 + 16 * nt];

        // ---- query tile pairs ----
        float* outS = out + (size_t)s * 16384;
        short8 Bh0, Bl0, Bh1, Bl1;
#pragma unroll 1
        for (int p = 0; p < 2; ++p) {
            f32x4 accA[4], accB[4];
            Ah0 = *(const short8*)(XA + aoff0);
            Al0 = *(const short8*)(XA + 2048 + aoff0);
            Ah1 = *(const short8*)(XA + aoff1);
            Al1 = *(const short8*)(XA + 2048 + aoff1);
            Bh0 = *(const short8*)(XB + aoff0);
            Bl0 = *(const short8*)(XB + 2048 + aoff0);
            Bh1 = *(const short8*)(XB + aoff1);
            Bl1 = *(const short8*)(XB + 2048 + aoff1);
#pragma unroll
            for (int nt = 0; nt < 4; ++nt) { accA[nt] = mk4(0.f); accB[nt] = mk4(0.f); }
            GEMM6_LDS_PAIR(accA, Ah0, Al0, Ah1, Al1, accB, Bh0, Bl0, Bh1, Bl1, smem + L_W1T);
            RELU4(accA); RELU4(accB);
            STORE_H(XA, accA);
            STORE_H(XB, accB);

            READ_A(XA, Ah0, Al0, Ah1, Al1);
            READ_A(XB, Bh0, Bl0, Bh1, Bl1);
#pragma unroll
            for (int nt = 0; nt < 4; ++nt) { accA[nt] = mk4(b2v[nt]); accB[nt] = mk4(b2v[nt]); }
            GEMM6_REG(accA, Ah0, Al0, Ah1, Al1, w2h, w2l);
            GEMM6_REG(accB, Bh0, Bl0, Bh1, Bl1, w2h, w2l);
            RELU4(accA); RELU4(accB);
            STORE_H(XA, accA);
            STORE_H(XB, accB);

            READ_A(XA, Ah0, Al0, Ah1, Al1);
            READ_A(XB, Bh0, Bl0, Bh1, Bl1);
#pragma unroll
            for (int nt = 0; nt < 4; ++nt) { accA[nt] = mk4(ckreg[nt]); accB[nt] = mk4(ckreg[nt]); }
            GEMM6_LDS_PAIR(accA, Ah0, Al0, Ah1, Al1, accB, Bh0, Bl0, Bh1, Bl1, smem + L_G);

            if (p == 0) {
                pe_values(vA, target_poses + ((size_t)(s * 256 + (8 + w) * 16 + l15)) * 16, g);
                writeA16(XA, l15, swz, g, vA);
                pe_values(vB, target_poses + ((size_t)(s * 256 + (12 + w) * 16 + l15)) * 16, g);
                writeA16(XB, l15, swz, g, vB);
            }

            const int qoffA = (p * 8 + w) * 16 + q4;
            const int qoffB = (p * 8 + 4 + w) * 16 + q4;
            SOFTMAX_STORE(accA, qoffA);
            SOFTMAX_STORE(accB, qoffB);
        }
    }
}

extern "C" void kernel_launch(void* const* d_in, const int* in_sizes, int n_in,
                              void* d_out, int out_size, void* d_ws, size_t ws_size,
                              hipStream_t stream) {
    const float* input_poses  = (const float*)d_in[0];
    const float* target_poses = (const float*)d_in[1];
    const float* W1 = (const float*)d_in[2];
    const float* b1 = (const float*)d_in[3];
    const float* W2 = (const float*)d_in[4];
    const float* b2 = (const float*)d_in[5];
    const float* W3 = (const float*)d_in[6];
    const float* b3 = (const float*)d_in[7];
    float* out = (float*)d_out;

    cam_mfma_kernel<<<dim3(512), dim3(256), 0, stream>>>(
        input_poses, target_poses, W1, b1, W2, b2, W3, b3, out);
}

// Round 17
// 53.286 us; speedup vs baseline: 1.0246x; 1.0246x over previous
//
#include <hip/hip_runtime.h>
#include <math.h>

typedef __attribute__((ext_vector_type(8))) short short8;
typedef __attribute__((ext_vector_type(4))) float f32x4;

#define SCALE 0.08838834764831845f   // 1/sqrt(128)

// LDS: W1T hi/lo 16K | L_G: W2T-scratch -> G -> Zk (hi/lo 16K) |
//      L_XH: W3-scratch (32K) -> 4 waves x 2 A-planes x 4K | ck | g
#define L_W1T 0
#define L_G   16384
#define L_XH  32768
#define L_CK  65536
#define L_g2  65792
#define LDS_BYTES 66048

__device__ __forceinline__ f32x4 mk4(float v) { f32x4 r = {v, v, v, v}; return r; }
union U4S8 { uint4 u4; unsigned u[4]; short8 s; };

// hi word from two raw f32 bit-patterns + lo word from trunc residuals
#define RESID2(DH, DL, UA, UB) do {                                     \
    (DH) = __builtin_amdgcn_perm((UB), (UA), 0x07060302u);              \
    float _ra = __uint_as_float(UA) - __uint_as_float((UA) & 0xffff0000u); \
    float _rb = __uint_as_float(UB) - __uint_as_float((UB) & 0xffff0000u); \
    (DL) = __builtin_amdgcn_perm(__float_as_uint(_rb),                  \
                                 __float_as_uint(_ra), 0x07060302u);    \
} while (0)

// two uint4 of raw f32 -> hi/lo short8 frags
#define SPLIT8R(SH, SL, A, B) do {                                      \
    U4S8 _th, _tl;                                                      \
    RESID2(_th.u[0], _tl.u[0], (A).x, (A).y);                           \
    RESID2(_th.u[1], _tl.u[1], (A).z, (A).w);                           \
    RESID2(_th.u[2], _tl.u[2], (B).x, (B).y);                           \
    RESID2(_th.u[3], _tl.u[3], (B).z, (B).w);                           \
    SH = _th.s; SL = _tl.s;                                             \
} while (0)

// ---- DPP 16-lane reductions (row_ror tree, pure VALU) ----
#define DPP_ROR(V, CTRL) \
    __int_as_float(__builtin_amdgcn_update_dpp(0, __float_as_int(V), (CTRL), 0xf, 0xf, true))
#define RED16_MAX(M) do {                                               \
    (M) = fmaxf((M), DPP_ROR((M), 0x128));                              \
    (M) = fmaxf((M), DPP_ROR((M), 0x124));                              \
    (M) = fmaxf((M), DPP_ROR((M), 0x122));                              \
    (M) = fmaxf((M), DPP_ROR((M), 0x121));                              \
} while (0)
#define RED16_SUM(S) do {                                               \
    (S) += DPP_ROR((S), 0x128);                                         \
    (S) += DPP_ROR((S), 0x124);                                         \
    (S) += DPP_ROR((S), 0x122);                                         \
    (S) += DPP_ROR((S), 0x121);                                         \
} while (0)

#define RELU4(ACC) do {                                                  \
    _Pragma("unroll")                                                    \
    for (int _n = 0; _n < 4; ++_n) {                                     \
        _Pragma("unroll")                                                \
        for (int _r = 0; _r < 4; ++_r)                                   \
            (ACC)[_n][_r] = fmaxf((ACC)[_n][_r], 0.f);                   \
    }                                                                    \
} while (0)

// ---- per-quarter PE + bias feature 42 = 1.0 (uniform sincos) ----
__device__ __forceinline__ void pe_values(float* v, const float* __restrict__ pose, int qt) {
    float2 r0 = *(const float2*)(pose + 2);
    float2 r1 = *(const float2*)(pose + 6);
    float2 r2 = *(const float2*)(pose + 10);
    const float L[3] = {r0.y, r1.y, r2.y};
    const float sc = (qt == 0) ? 1.5f : ((qt == 1) ? 6.f : 24.f);
    float s0[3], c0[3], s1[3], c1[3], s2[3], c2[3];
#pragma unroll
    for (int c = 0; c < 3; ++c) {
        __sincosf(sc * L[c], &s0[c], &c0[c]);
        s1[c] = 2.f * s0[c] * c0[c];
        c1[c] = fmaf(c0[c], c0[c], -s0[c] * s0[c]);
        s2[c] = 2.f * s1[c] * c1[c];
        c2[c] = fmaf(c1[c], c1[c], -s1[c] * s1[c]);
    }
    if (qt == 0) {
        v[0]=L[0]; v[1]=L[1]; v[2]=L[2];
        v[3]=s0[0]; v[4]=s0[1]; v[5]=s0[2];
        v[6]=c0[0]; v[7]=c0[1]; v[8]=c0[2];
        v[9]=s1[0]; v[10]=s1[1]; v[11]=s1[2];
        v[12]=c1[0]; v[13]=c1[1]; v[14]=c1[2];
        v[15]=s2[0];
    } else if (qt == 1) {
        v[0]=s0[1]; v[1]=s0[2];
        v[2]=c0[0]; v[3]=c0[1]; v[4]=c0[2];
        v[5]=s1[0]; v[6]=s1[1]; v[7]=s1[2];
        v[8]=c1[0]; v[9]=c1[1]; v[10]=c1[2];
        v[11]=s2[0]; v[12]=s2[1]; v[13]=s2[2];
        v[14]=c2[0]; v[15]=c2[1];
    } else if (qt == 2) {
        v[0]=c0[2];
        v[1]=s1[0]; v[2]=s1[1]; v[3]=s1[2];
        v[4]=c1[0]; v[5]=c1[1]; v[6]=c1[2];
        v[7]=r0.x; v[8]=r1.x; v[9]=r2.x;
        v[10]=1.0f;   // bias feature 42
        v[11]=0.f; v[12]=0.f; v[13]=0.f; v[14]=0.f; v[15]=0.f;
    } else {
#pragma unroll
        for (int t = 0; t < 16; ++t) v[t] = 0.f;
    }
}

// pack v[16] -> X hi/lo halves of a 4K plane (bf16 planes, frag-ready)
__device__ __forceinline__ void writeA16(char* X, int l15, int swz, int qt, const float* v) {
    unsigned h[8], l[8];
#pragma unroll
    for (int p = 0; p < 8; ++p) {
        float a = v[2 * p], b = v[2 * p + 1];
        unsigned ua = __float_as_uint(a), ub = __float_as_uint(b);
        h[p] = (ub & 0xffff0000u) | (ua >> 16);
        float ra = a - __uint_as_float(ua & 0xffff0000u);
        float rb = b - __uint_as_float(ub & 0xffff0000u);
        l[p] = (__float_as_uint(rb) & 0xffff0000u) | (__float_as_uint(ra) >> 16);
    }
    const int cb = qt * 32;
    const int a1 = l15 * 128 + (cb ^ swz);
    const int a2 = l15 * 128 + ((cb + 16) ^ swz);
    *(uint4*)(X + a1) = make_uint4(h[0], h[1], h[2], h[3]);
    *(uint4*)(X + a2) = make_uint4(h[4], h[5], h[6], h[7]);
    *(uint4*)(X + 2048 + a1) = make_uint4(l[0], l[1], l[2], l[3]);
    *(uint4*)(X + 2048 + a2) = make_uint4(l[4], l[5], l[6], l[7]);
}

// A-frags (both ks) from RAW-f32 H plane: 4 b128 reads + trunc-split reconstruct
#define READ_A(H, Ah0, Al0, Ah1, Al1) do {                              \
    uint4 _a = *(const uint4*)((H) + hb00);                             \
    uint4 _b = *(const uint4*)((H) + hb01);                             \
    uint4 _c = *(const uint4*)((H) + hb10);                             \
    uint4 _d = *(const uint4*)((H) + hb11);                             \
    SPLIT8R(Ah0, Al0, _a, _b);                                          \
    SPLIT8R(Ah1, Al1, _c, _d);                                          \
} while (0)

// single-tile hi/lo gemm, B planes in LDS (hi @BP, lo @BP+8192)
#define GEMM6_LDS(ACC, Ah0, Al0, Ah1, Al1, BP) do {                     \
    _Pragma("unroll")                                                   \
    for (int _nt = 0; _nt < 4; ++_nt) {                                 \
        const char* _b = (BP) + _nt * 2048;                             \
        short8 _bh0 = *(const short8*)(_b + aoff0);                     \
        short8 _bl0 = *(const short8*)(_b + 8192 + aoff0);              \
        short8 _bh1 = *(const short8*)(_b + aoff1);                     \
        short8 _bl1 = *(const short8*)(_b + 8192 + aoff1);              \
        f32x4 _x = (ACC)[_nt];                                          \
        _x = __builtin_amdgcn_mfma_f32_16x16x32_bf16(Ah0, _bh0, _x, 0, 0, 0); \
        _x = __builtin_amdgcn_mfma_f32_16x16x32_bf16(Ah0, _bl0, _x, 0, 0, 0); \
        _x = __builtin_amdgcn_mfma_f32_16x16x32_bf16(Al0, _bh0, _x, 0, 0, 0); \
        _x = __builtin_amdgcn_mfma_f32_16x16x32_bf16(Ah1, _bh1, _x, 0, 0, 0); \
        _x = __builtin_amdgcn_mfma_f32_16x16x32_bf16(Ah1, _bl1, _x, 0, 0, 0); \
        _x = __builtin_amdgcn_mfma_f32_16x16x32_bf16(Al1, _bh1, _x, 0, 0, 0); \
        (ACC)[_nt] = _x;                                                \
    }                                                                   \
} while (0)

// pair gemm: B-frags read ONCE from LDS, feed both tiles
#define GEMM6_LDS_PAIR(ACCA, Aa0, Aal0, Aa1, Aal1, ACCB, Bb0, Bbl0, Bb1, Bbl1, BP) do { \
    _Pragma("unroll")                                                   \
    for (int _nt = 0; _nt < 4; ++_nt) {                                 \
        const char* _b = (BP) + _nt * 2048;                             \
        short8 _bh0 = *(const short8*)(_b + aoff0);                     \
        short8 _bl0 = *(const short8*)(_b + 8192 + aoff0);              \
        short8 _bh1 = *(const short8*)(_b + aoff1);                     \
        short8 _bl1 = *(const short8*)(_b + 8192 + aoff1);              \
        f32x4 _x = (ACCA)[_nt];                                         \
        _x = __builtin_amdgcn_mfma_f32_16x16x32_bf16(Aa0, _bh0, _x, 0, 0, 0); \
        _x = __builtin_amdgcn_mfma_f32_16x16x32_bf16(Aa0, _bl0, _x, 0, 0, 0); \
        _x = __builtin_amdgcn_mfma_f32_16x16x32_bf16(Aal0, _bh0, _x, 0, 0, 0); \
        _x = __builtin_amdgcn_mfma_f32_16x16x32_bf16(Aa1, _bh1, _x, 0, 0, 0); \
        _x = __builtin_amdgcn_mfma_f32_16x16x32_bf16(Aa1, _bl1, _x, 0, 0, 0); \
        _x = __builtin_amdgcn_mfma_f32_16x16x32_bf16(Aal1, _bh1, _x, 0, 0, 0); \
        (ACCA)[_nt] = _x;                                               \
        f32x4 _y = (ACCB)[_nt];                                         \
        _y = __builtin_amdgcn_mfma_f32_16x16x32_bf16(Bb0, _bh0, _y, 0, 0, 0); \
        _y = __builtin_amdgcn_mfma_f32_16x16x32_bf16(Bb0, _bl0, _y, 0, 0, 0); \
        _y = __builtin_amdgcn_mfma_f32_16x16x32_bf16(Bbl0, _bh0, _y, 0, 0, 0); \
        _y = __builtin_amdgcn_mfma_f32_16x16x32_bf16(Bb1, _bh1, _y, 0, 0, 0); \
        _y = __builtin_amdgcn_mfma_f32_16x16x32_bf16(Bb1, _bl1, _y, 0, 0, 0); \
        _y = __builtin_amdgcn_mfma_f32_16x16x32_bf16(Bbl1, _bh1, _y, 0, 0, 0); \
        (ACCB)[_nt] = _y;                                               \
    }                                                                   \
} while (0)

// hi/lo gemm, B fragments in registers (W2T)
#define GEMM6_REG(ACC, Ah0, Al0, Ah1, Al1, Bh, Bl) do {                 \
    _Pragma("unroll")                                                   \
    for (int _nt = 0; _nt < 4; ++_nt) {                                 \
        f32x4 _x = (ACC)[_nt];                                          \
        _x = __builtin_amdgcn_mfma_f32_16x16x32_bf16(Ah0, (Bh)[0][_nt], _x, 0, 0, 0); \
        _x = __builtin_amdgcn_mfma_f32_16x16x32_bf16(Ah0, (Bl)[0][_nt], _x, 0, 0, 0); \
        _x = __builtin_amdgcn_mfma_f32_16x16x32_bf16(Al0, (Bh)[0][_nt], _x, 0, 0, 0); \
        _x = __builtin_amdgcn_mfma_f32_16x16x32_bf16(Ah1, (Bh)[1][_nt], _x, 0, 0, 0); \
        _x = __builtin_amdgcn_mfma_f32_16x16x32_bf16(Ah1, (Bl)[1][_nt], _x, 0, 0, 0); \
        _x = __builtin_amdgcn_mfma_f32_16x16x32_bf16(Al1, (Bh)[1][_nt], _x, 0, 0, 0); \
        (ACC)[_nt] = _x;                                                \
    }                                                                   \
} while (0)

// C-tile -> RAW-f32 H plane (16 plain b32 writes), swizzled
#define STORE_H(H, ACC) do {                                            \
    _Pragma("unroll")                                                   \
    for (int _nt = 0; _nt < 4; ++_nt) {                                 \
        _Pragma("unroll")                                               \
        for (int _r = 0; _r < 4; ++_r) {                                \
            int _row = q4 + _r;                                         \
            int _byte = _row * 256 + ((((l15 + 16 * _nt) << 2)) ^ ((_row & 7) << 4)); \
            *(float*)((H) + _byte) = (ACC)[_nt][_r];                    \
        }                                                               \
    }                                                                   \
} while (0)

#define SOFTMAX_STORE(ACC, QOFF) do {                                   \
    _Pragma("unroll")                                                   \
    for (int _r = 0; _r < 4; ++_r) {                                    \
        float _m = fmaxf(fmaxf((ACC)[0][_r], (ACC)[1][_r]),             \
                         fmaxf((ACC)[2][_r], (ACC)[3][_r]));            \
        RED16_MAX(_m);                                                  \
        float _e0 = __expf(((ACC)[0][_r] - _m) * SCALE);                \
        float _e1 = __expf(((ACC)[1][_r] - _m) * SCALE);                \
        float _e2 = __expf(((ACC)[2][_r] - _m) * SCALE);                \
        float _e3 = __expf(((ACC)[3][_r] - _m) * SCALE);                \
        float _ss = _e0 + _e1 + _e2 + _e3;                              \
        RED16_SUM(_ss);                                                 \
        float _iv = 1.f / _ss;                                          \
        (ACC)[0][_r] = _e0 * _iv; (ACC)[1][_r] = _e1 * _iv;             \
        (ACC)[2][_r] = _e2 * _iv; (ACC)[3][_r] = _e3 * _iv;             \
    }                                                                   \
    _Pragma("unroll")                                                   \
    for (int _nt = 0; _nt < 4; ++_nt) {                                 \
        int _k = l15 + 16 * _nt;                                        \
        *(float4*)(outS + (size_t)_k * 256 + (QOFF)) =                  \
            make_float4((ACC)[_nt][0], (ACC)[_nt][1],                   \
                        (ACC)[_nt][2], (ACC)[_nt][3]);                  \
    }                                                                   \
} while (0)

// -------- single fused kernel: LDS-clean weight prep + MFMA attention --------
__global__ __launch_bounds__(256, 2) void cam_mfma_kernel(
    const float* __restrict__ input_poses, const float* __restrict__ target_poses,
    const float* __restrict__ W1, const float* __restrict__ b1,
    const float* __restrict__ W2, const float* __restrict__ b2,
    const float* __restrict__ W3, const float* __restrict__ b3,
    float* __restrict__ out)
{
    __shared__ __align__(16) char smem[LDS_BYTES];
    const int tid = threadIdx.x, lane = tid & 63, w = tid >> 6, s = blockIdx.x;
    const int l15 = lane & 15, g = lane >> 4, q4 = g << 2;
    const int swz = (l15 & 7) << 4;
    const int aoff0 = l15 * 128 + ((g << 4) ^ swz);           // frag offsets (X & B planes)
    const int aoff1 = l15 * 128 + ((64 + (g << 4)) ^ swz);
    const int hb00 = l15 * 256 + ((32 * g) ^ swz);            // H plane chunks
    const int hb01 = l15 * 256 + ((32 * g + 16) ^ swz);
    const int hb10 = l15 * 256 + ((32 * g + 128) ^ swz);
    const int hb11 = l15 * 256 + ((32 * g + 128 + 16) ^ swz);

    char* ZK = smem + L_G;
    char* XA = smem + L_XH + (w << 13);          // plane A (4K), after W3 scratch dies
    char* XB = XA + 4096;                        // plane B (4K)
    float* ckF = (float*)(smem + L_CK);
    float* gF  = (float*)(smem + L_g2);

    // ---- phase P1: coalesced staging ----
    // W3 raw f32 -> XH scratch, 16B-granule swizzle: addr = row*512 + (cb ^ ((row&7)<<4))
    {
        const uint4* src = (const uint4*)W3;
#pragma unroll
        for (int it = 0; it < 8; ++it) {
            int idx = tid + it * 256;               // 2048 uint4
            int row = idx >> 5, c4 = idx & 31;
            *(uint4*)(smem + L_XH + row * 512 + ((c4 * 16) ^ ((row & 7) << 4))) = src[idx];
        }
    }
    // W1T (+bias col 42) -> L_W1T, W2T -> L_G scratch; u32-paired trunc-split writes
#pragma unroll
    for (int it = 0; it < 8; ++it) {
        int e = tid + it * 256;                     // 2048 pairs
        int i = e & 63, jp = e >> 6;                // j0 = 2jp, j1 = 2jp+1
        int j0 = jp * 2, j1 = j0 + 1;
        float v0 = (j0 < 42) ? W1[j0 * 64 + i] : ((j0 == 42) ? b1[i] : 0.f);
        float v1 = (j1 < 42) ? W1[j1 * 64 + i] : ((j1 == 42) ? b1[i] : 0.f);
        unsigned dh, dl;
        RESID2(dh, dl, __float_as_uint(v0), __float_as_uint(v1));
        int a = i * 128 + ((jp * 4) ^ ((i & 7) << 4));
        *(unsigned*)(smem + L_W1T + a) = dh;
        *(unsigned*)(smem + L_W1T + 8192 + a) = dl;
        float u0 = W2[j0 * 64 + i], u1 = W2[j1 * 64 + i];
        RESID2(dh, dl, __float_as_uint(u0), __float_as_uint(u1));
        *(unsigned*)(smem + L_G + a) = dh;          // W2T scratch
        *(unsigned*)(smem + L_G + 8192 + a) = dl;
    }
    // g = W3 b3 (lanes < 64, from global; overlaps staging)
    if (tid < 64) {
        const float4* wr = (const float4*)(W3 + tid * 128);
        const float4* br = (const float4*)b3;
        float a0 = 0.f, a1 = 0.f, a2 = 0.f, a3 = 0.f;
#pragma unroll 8
        for (int c = 0; c < 32; ++c) {
            float4 x = wr[c], y = br[c];
            a0 = fmaf(x.x, y.x, a0);
            a1 = fmaf(x.y, y.y, a1);
            a2 = fmaf(x.z, y.z, a2);
            a3 = fmaf(x.w, y.w, a3);
        }
        gF[tid] = (a0 + a1) + (a2 + a3);
    }
    __syncthreads();   // barrier A: W3/W1T/W2T staged, g ready

    // ---- phase P2: w2r frags from L_G scratch; G = W3 W3^T slice via MFMA (from LDS) ----
    short8 w2h[2][4], w2l[2][4];
#pragma unroll
    for (int ks = 0; ks < 2; ++ks)
#pragma unroll
        for (int nt = 0; nt < 4; ++nt) {
            const char* bsc = smem + L_G + nt * 2048 + (ks ? aoff1 : aoff0);
            w2h[ks][nt] = *(const short8*)(bsc);
            w2l[ks][nt] = *(const short8*)(bsc + 8192);
        }
    f32x4 gacc[4];
    {
#pragma unroll
        for (int nt = 0; nt < 4; ++nt) gacc[nt] = mk4(0.f);
        const char* W3L = smem + L_XH;
        const int ra = 16 * w + l15;
#pragma unroll
        for (int ks = 0; ks < 4; ++ks) {
            const int cb = g * 32 + ks * 128;
            uint4 a0 = *(const uint4*)(W3L + ra * 512 + (cb ^ ((ra & 7) << 4)));
            uint4 a1 = *(const uint4*)(W3L + ra * 512 + ((cb + 16) ^ ((ra & 7) << 4)));
            short8 ah, al;
            SPLIT8R(ah, al, a0, a1);
#pragma unroll
            for (int nt = 0; nt < 4; ++nt) {
                const int rb = l15 + 16 * nt;
                uint4 b0 = *(const uint4*)(W3L + rb * 512 + (cb ^ ((rb & 7) << 4)));
                uint4 b1_ = *(const uint4*)(W3L + rb * 512 + ((cb + 16) ^ ((rb & 7) << 4)));
                short8 bh, bl;
                SPLIT8R(bh, bl, b0, b1_);
                f32x4 x = gacc[nt];
                x = __builtin_amdgcn_mfma_f32_16x16x32_bf16(ah, bh, x, 0, 0, 0);
                x = __builtin_amdgcn_mfma_f32_16x16x32_bf16(ah, bl, x, 0, 0, 0);
                x = __builtin_amdgcn_mfma_f32_16x16x32_bf16(al, bh, x, 0, 0, 0);
                gacc[nt] = x;
            }
        }
    }
    float b2v[4], gw[4];
#pragma unroll
    for (int nt = 0; nt < 4; ++nt) {
        b2v[nt] = b2[l15 + 16 * nt];
        gw[nt]  = gF[l15 + 16 * nt];
    }
    short8 Ah0, Al0, Ah1, Al1;
    float vA[16], vB[16];
    pe_values(vA, input_poses + ((size_t)(s * 64 + 16 * w + l15)) * 16, g);
    __syncthreads();   // barrier B: w2r loaded, W3/W2T scratch dead

    // scatter G slice -> L_G (symmetric: row-store == required col layout)
#pragma unroll
    for (int nt = 0; nt < 4; ++nt) {
#pragma unroll
        for (int r = 0; r < 4; ++r) {
            int row = 16 * w + q4 + r;
            int byte = row * 128 + (((l15 + 16 * nt) * 2) ^ ((row & 7) << 4));
            float gv2 = gacc[nt][r];
            unsigned u = __float_as_uint(gv2);
            *(unsigned short*)(smem + L_G + byte) = (unsigned short)(u >> 16);
            float res = gv2 - __uint_as_float(u & 0xffff0000u);
            *(unsigned short*)(smem + L_G + 8192 + byte) =
                (unsigned short)(__float_as_uint(res) >> 16);
        }
    }

    // ================= key tile (wave w -> keys 16w..16w+15) =================
    f32x4 zacc[4];
    {
        writeA16(XA, l15, swz, g, vA);
        Ah0 = *(const short8*)(XA + aoff0);
        Al0 = *(const short8*)(XA + 2048 + aoff0);
        Ah1 = *(const short8*)(XA + aoff1);
        Al1 = *(const short8*)(XA + 2048 + aoff1);
        f32x4 acc[4];
#pragma unroll
        for (int nt = 0; nt < 4; ++nt) acc[nt] = mk4(0.f);
        GEMM6_LDS(acc, Ah0, Al0, Ah1, Al1, smem + L_W1T);   // L1 (bias via K-col)
        RELU4(acc);
        STORE_H(XA, acc);                                    // H1 (raw f32)

        READ_A(XA, Ah0, Al0, Ah1, Al1);
#pragma unroll
        for (int nt = 0; nt < 4; ++nt) acc[nt] = mk4(b2v[nt]);
        GEMM6_REG(acc, Ah0, Al0, Ah1, Al1, w2h, w2l);        // L2
        RELU4(acc);

        // ck[key] = g . h2k  (DPP 16-lane sum)
#pragma unroll
        for (int r = 0; r < 4; ++r) {
            float t = acc[0][r] * gw[0];
            t = fmaf(acc[1][r], gw[1], t);
            t = fmaf(acc[2][r], gw[2], t);
            t = fmaf(acc[3][r], gw[3], t);
            RED16_SUM(t);
            if (l15 == 0) ckF[16 * w + q4 + r] = t;
        }
        STORE_H(XA, acc);                                    // H2 (raw f32)

        READ_A(XA, Ah0, Al0, Ah1, Al1);
#pragma unroll
        for (int nt = 0; nt < 4; ++nt) zacc[nt] = mk4(0.f);
        __syncthreads();   // barrier C: all waves' G scatter visible
        GEMM6_LDS(zacc, Ah0, Al0, Ah1, Al1, smem + L_G);     // Zk = H2k @ G
    }
    // prefetch query tile pair 0 PE (fills barrier shadow)
    pe_values(vA, target_poses + ((size_t)(s * 256 + (w) * 16 + l15)) * 16, g);
    pe_values(vB, target_poses + ((size_t)(s * 256 + (4 + w) * 16 + l15)) * 16, g);
    __syncthreads();   // barrier 1: all G reads + ck writes done

    // scatter Zk tile over G (trunc hi/lo), swizzled B-plane layout
#pragma unroll
    for (int nt = 0; nt < 4; ++nt) {
#pragma unroll
        for (int r = 0; r < 4; ++r) {
            int row = 16 * w + q4 + r;
            int byte = row * 128 + (((l15 + 16 * nt) * 2) ^ ((row & 7) << 4));
            float zv = zacc[nt][r];
            unsigned u = __float_as_uint(zv);
            *(unsigned short*)(ZK + byte) = (unsigned short)(u >> 16);
            float res = zv - __uint_as_float(u & 0xffff0000u);
            *(unsigned short*)(ZK + 8192 + byte) = (unsigned short)(__float_as_uint(res) >> 16);
        }
    }
    writeA16(XA, l15, swz, g, vA);     // pair-0 A tiles (own planes)
    writeA16(XB, l15, swz, g, vB);
    __syncthreads();   // barrier 2: Zk + ck visible
    float ckreg[4];
#pragma unroll
    for (int nt = 0; nt < 4; ++nt) ckreg[nt] = ckF[l15 + 16 * nt];

    // ========= query tile pairs: wave w does tiles (8p+w, 8p+4+w), p=0,1 =========
    float* outS = out + (size_t)s * 16384;
    short8 Bh0, Bl0, Bh1, Bl1;
#pragma unroll 1
    for (int p = 0; p < 2; ++p) {
        f32x4 accA[4], accB[4];
        // ---- phase 1: L1 both tiles, B-frags read once ----
        Ah0 = *(const short8*)(XA + aoff0);
        Al0 = *(const short8*)(XA + 2048 + aoff0);
        Ah1 = *(const short8*)(XA + aoff1);
        Al1 = *(const short8*)(XA + 2048 + aoff1);
        Bh0 = *(const short8*)(XB + aoff0);
        Bl0 = *(const short8*)(XB + 2048 + aoff0);
        Bh1 = *(const short8*)(XB + aoff1);
        Bl1 = *(const short8*)(XB + 2048 + aoff1);
#pragma unroll
        for (int nt = 0; nt < 4; ++nt) { accA[nt] = mk4(0.f); accB[nt] = mk4(0.f); }
        GEMM6_LDS_PAIR(accA, Ah0, Al0, Ah1, Al1, accB, Bh0, Bl0, Bh1, Bl1, smem + L_W1T);
        RELU4(accA); RELU4(accB);
        STORE_H(XA, accA);
        STORE_H(XB, accB);

        // ---- phase 2: L2 both tiles (B in registers) ----
        READ_A(XA, Ah0, Al0, Ah1, Al1);
        READ_A(XB, Bh0, Bl0, Bh1, Bl1);
#pragma unroll
        for (int nt = 0; nt < 4; ++nt) { accA[nt] = mk4(b2v[nt]); accB[nt] = mk4(b2v[nt]); }
        GEMM6_REG(accA, Ah0, Al0, Ah1, Al1, w2h, w2l);
        GEMM6_REG(accB, Bh0, Bl0, Bh1, Bl1, w2h, w2l);
        RELU4(accA); RELU4(accB);
        STORE_H(XA, accA);
        STORE_H(XB, accB);

        // ---- phase 3: scores both tiles, shared Zk B-frags ----
        READ_A(XA, Ah0, Al0, Ah1, Al1);
        READ_A(XB, Bh0, Bl0, Bh1, Bl1);
#pragma unroll
        for (int nt = 0; nt < 4; ++nt) { accA[nt] = mk4(ckreg[nt]); accB[nt] = mk4(ckreg[nt]); }
        GEMM6_LDS_PAIR(accA, Ah0, Al0, Ah1, Al1, accB, Bh0, Bl0, Bh1, Bl1, smem + L_G);

        // prefetch next pair PE + A-writes (planes free after the READ_As above)
        if (p == 0) {
            pe_values(vA, target_poses + ((size_t)(s * 256 + (8 + w) * 16 + l15)) * 16, g);
            writeA16(XA, l15, swz, g, vA);
            pe_values(vB, target_poses + ((size_t)(s * 256 + (12 + w) * 16 + l15)) * 16, g);
            writeA16(XB, l15, swz, g, vB);
        }

        // ---- softmax (DPP) + transposed stores ----
        const int qoffA = (p * 8 + w) * 16 + q4;
        const int qoffB = (p * 8 + 4 + w) * 16 + q4;
        SOFTMAX_STORE(accA, qoffA);
        SOFTMAX_STORE(accB, qoffB);
    }
}

extern "C" void kernel_launch(void* const* d_in, const int* in_sizes, int n_in,
                              void* d_out, int out_size, void* d_ws, size_t ws_size,
                              hipStream_t stream) {
    const float* input_poses  = (const float*)d_in[0];
    const float* target_poses = (const float*)d_in[1];
    const float* W1 = (const float*)d_in[2];
    const float* b1 = (const float*)d_in[3];
    const float* W2 = (const float*)d_in[4];
    const float* b2 = (const float*)d_in[5];
    const float* W3 = (const float*)d_in[6];
    const float* b3 = (const float*)d_in[7];
    float* out = (float*)d_out;

    cam_mfma_kernel<<<dim3(1024), dim3(256), 0, stream>>>(
        input_poses, target_poses, W1, b1, W2, b2, W3, b3, out);
}